// Round 19
// baseline (113.426 us; speedup 1.0000x reference)
//
#include <hip/hip_runtime.h>
#include <hip/hip_bf16.h>
#include <stdint.h>

typedef _Float16 f16x8_t  __attribute__((ext_vector_type(8)));
typedef float    f32x16_t __attribute__((ext_vector_type(16)));
typedef short    s16x8_t  __attribute__((ext_vector_type(8)));
typedef unsigned uint2v   __attribute__((ext_vector_type(2)));
typedef unsigned int u32;

#define MFMA32 __builtin_amdgcn_mfma_f32_32x32x16_f16

#if __has_builtin(__builtin_amdgcn_exp2f)
#define EXP2(x) __builtin_amdgcn_exp2f(x)
#else
#define EXP2(x) exp2f(x)
#endif

__device__ __forceinline__ u32 PKRTZ(float a, float b) {
    return __builtin_bit_cast(u32, __builtin_amdgcn_cvt_pkrtz(a, b));
}

__device__ __forceinline__ void PLSWAP(u32& a, u32& b) {
#if __has_builtin(__builtin_amdgcn_permlane32_swap)
    uint2v r = __builtin_amdgcn_permlane32_swap(a, b, false, false);
    a = r[0]; b = r[1];
#else
    u32 pa = (u32)__shfl_xor((int)a, 32);
    u32 pb = (u32)__shfl_xor((int)b, 32);
    const int hi_ = (int)((threadIdx.x & 63) >> 5);
    u32 na = hi_ ? pb : a;
    u32 nb = hi_ ? b  : pa;
    a = na; b = nb;
#endif
}
__device__ __forceinline__ float swap_add(float v) {   // own + partner(lane^32)
    u32 a = __builtin_bit_cast(u32, v), b = a;
    PLSWAP(a, b);
    return __builtin_bit_cast(float, a) + __builtin_bit_cast(float, b);
}
__device__ __forceinline__ float swap_max(float v) {
    u32 a = __builtin_bit_cast(u32, v), b = a;
    PLSWAP(a, b);
    return fmaxf(__builtin_bit_cast(float, a), __builtin_bit_cast(float, b));
}

constexpr int Bb   = 16;
constexpr int HIDc = 512;
constexpr int SEQc = 1024;

constexpr int QT = 128;            // q rows per block (4 groups x 32; 2 KV-halves)
constexpr int KT = 64;             // kv rows per tile
constexpr int HTILES = 8;          // tiles per KV-half (512 rows / 64)

constexpr float LOG2E_F = 1.4426950408889634f;
constexpr float DTHR    = 11.5f;   // defer-max threshold (log2 domain)
constexpr float NEG_INF = -1e30f;

constexpr int ROWB        = 144;              // 72 f16 per row
constexpr int VT_OFF      = 64 * ROWB;        // 9216 (within buffer)
constexpr int BUF_STRIDE  = 2 * VT_OFF;       // 18432 (K + Vt)
constexpr int HALF_STRIDE = 2 * BUF_STRIDE;   // 36864 (dbuf per half)
constexpr int LDS_TOTAL   = 2 * HALF_STRIDE;  // 73728; merge(34816)+fp(34816) reuse it

__global__ __launch_bounds__(512, 4)   // 8 waves; 128-VGPR cap (R12-proven clean)
void xattn_kernel(const float* __restrict__ X, const float* __restrict__ Y,
                  const float* __restrict__ padx, const float* __restrict__ pady,
                  float* __restrict__ out)
{
    __shared__ __align__(16) unsigned char pool[LDS_TOTAL];

    const int tid  = threadIdx.x;
    const int w    = tid >> 6;          // 0..7
    const int wg   = w & 3;             // q-group
    const int wh   = w >> 2;            // KV half (0/1)
    const int lane = tid & 63;
    const int l31  = lane & 31;
    const int hi   = lane >> 5;
    const unsigned hoff = (unsigned)(wh * HALF_STRIDE);

    // XCD-aware swizzle (nwg=2048, bijective): 8 q-tile blocks/KV-panel -> same XCD
    const unsigned hid = blockIdx.x + gridDim.x * (blockIdx.y + gridDim.y * blockIdx.z);
    const unsigned lid = (hid & 7u) * 256u + (hid >> 3);
    const int qt   = lid & 7;
    const int bh   = (lid >> 3) & 127;
    const int pass = lid >> 10;
    const int b    = bh >> 3;
    const int h    = bh & 7;

    // pass 0: Q=X, KV=[pad_y;Y] -> Y_in_X (output 1)
    // pass 1: Q=Y, KV=[pad_x;X] -> X_in_Y (output 0)
    const float* Qp   = pass == 0 ? X : Y;
    const float* KVp  = pass == 0 ? Y : X;
    const float* padp = pass == 0 ? pady : padx;
    float* outp = out + (pass == 0 ? (size_t)Bb * SEQc * HIDc : (size_t)0);

    // ---- Q fragments (B-operand 32x32x16): col=q=l31, slot(hi,j) -> d=ds*16+hi*8+j
    const float* qrow = Qp + ((size_t)b * SEQc + qt * QT + wg * 32 + l31) * HIDc + h * 64;
    f16x8_t qf[4];
#pragma unroll
    for (int ds = 0; ds < 4; ++ds) {
        const float* src = qrow + ds * 16 + hi * 8;
        float4 a = *(const float4*)src;
        float4 c = *(const float4*)(src + 4);
        uint4 uu = {PKRTZ(a.x * LOG2E_F, a.y * LOG2E_F), PKRTZ(a.z * LOG2E_F, a.w * LOG2E_F),
                    PKRTZ(c.x * LOG2E_F, c.y * LOG2E_F), PKRTZ(c.z * LOG2E_F, c.w * LOG2E_F)};
        qf[ds] = __builtin_bit_cast(f16x8_t, uu);
    }

    // ---- state init: half A gets the pad-row prologue, half B starts empty ---
    const float* padh = padp + h * 64;
    float mr, lr;
    f32x16_t Oacc[2];
    if (wh == 0) {
        float s0 = 0.f, s1 = 0.f;
#pragma unroll
        for (int ds = 0; ds < 4; ++ds)
#pragma unroll
            for (int j = 0; j < 8; ++j) {
                float qv = (float)qf[ds][j];
                int d = ds * 16 + hi * 8 + j;
                s0 += qv * padh[d];
                s1 += qv * padh[HIDc + d];
            }
        s0 = swap_add(s0);
        s1 = swap_add(s1);
        mr = fmaxf(s0, s1);
        float e0 = EXP2(s0 - mr), e1 = EXP2(s1 - mr);
        lr = e0 + e1;
#pragma unroll
        for (int db = 0; db < 2; ++db)
#pragma unroll
            for (int r = 0; r < 16; ++r) {
                int d = db * 32 + (r & 3) + 8 * (r >> 2) + 4 * hi;
                Oacc[db][r] = e0 * padh[d] + e1 * padh[HIDc + d];
            }
    } else {
        mr = NEG_INF;
        lr = 0.f;
#pragma unroll
        for (int db = 0; db < 2; ++db)
#pragma unroll
            for (int r = 0; r < 16; ++r) Oacc[db][r] = 0.f;
    }

    // ---- LDS read addresses (R12 scheme, within own half) -------------------
    const unsigned kkey = (unsigned)(((l31 >> 3) & 3) << 4);
    const unsigned vkey = (unsigned)((l31 >> 3) << 4);
    const unsigned rowb = (unsigned)(l31 * ROWB);
    unsigned kcol[4], vcol[4];
#pragma unroll
    for (int s = 0; s < 4; ++s) {
        kcol[s] = (unsigned)((s * 32 + hi * 16) ^ kkey);
        vcol[s] = (unsigned)(VT_OFF + ((s * 32 + hi * 16) ^ vkey));
    }

    // staging geometry: thread's half = wh; within-half 256 threads (R12-exact)
    const int tid8 = tid & 255;
    const int tr = tid8 >> 3, tc = tid8 & 7;
    const float* ksrc = KVp + ((size_t)b * SEQc + wh * 512 + 2 * tr) * HIDc + h * 64 + tc * 8;
    const unsigned kw  = (unsigned)((2 * tr) * ROWB + ((tc * 16) ^ ((((2 * tr) >> 3) & 3) << 4)));
    const unsigned vtw = (unsigned)(VT_OFF + (tc * 8) * ROWB + ((4 * tr) ^ (tc << 4)));

    // ---- helpers ------------------------------------------------------------
    auto loadtile = [&](int idx, float4& a0, float4& a1, float4& c0, float4& c1) {
        const float* srow = ksrc + (size_t)idx * KT * HIDc;
        a0 = *(const float4*)srow;          a1 = *(const float4*)(srow + 4);
        c0 = *(const float4*)(srow + HIDc); c1 = *(const float4*)(srow + HIDc + 4);
    };
    auto stage_write = [&](unsigned bo, const float4& a0, const float4& a1,
                           const float4& c0, const float4& c1) {
        uint4 k0 = {PKRTZ(a0.x, a0.y), PKRTZ(a0.z, a0.w), PKRTZ(a1.x, a1.y), PKRTZ(a1.z, a1.w)};
        uint4 k1 = {PKRTZ(c0.x, c0.y), PKRTZ(c0.z, c0.w), PKRTZ(c1.x, c1.y), PKRTZ(c1.z, c1.w)};
        *(uint4*)(pool + bo + kw) = k0;
        *(uint4*)(pool + bo + kw + ROWB) = k1;
        float fa[8] = {a0.x, a0.y, a0.z, a0.w, a1.x, a1.y, a1.z, a1.w};
        float fc[8] = {c0.x, c0.y, c0.z, c0.w, c1.x, c1.y, c1.z, c1.w};
#pragma unroll
        for (int j = 0; j < 8; ++j)
            *(u32*)(pool + bo + vtw + j * ROWB) = PKRTZ(fa[j], fc[j]);
    };

    auto compute = [&](unsigned bo) {
        // ---- S^T = K*Q^T via 32x32x16 (R12-exact) ---------------------------
        f32x16_t sa[2];
#pragma unroll
        for (int nb = 0; nb < 2; ++nb)
#pragma unroll
            for (int r = 0; r < 16; ++r) sa[nb][r] = 0.f;
        __builtin_amdgcn_s_setprio(1);
#pragma unroll
        for (int ds = 0; ds < 4; ++ds) {
            s16x8_t k0 = *(const s16x8_t*)(pool + bo + rowb + kcol[ds]);
            s16x8_t k1 = *(const s16x8_t*)(pool + bo + rowb + kcol[ds] + 32 * ROWB);
            sa[0] = MFMA32(__builtin_bit_cast(f16x8_t, k0), qf[ds], sa[0], 0, 0, 0);
            sa[1] = MFMA32(__builtin_bit_cast(f16x8_t, k1), qf[ds], sa[1], 0, 0, 0);
        }
        __builtin_amdgcn_s_setprio(0);

        // ---- softmax max-reduce (R12-exact) ---------------------------------
        float pm = sa[0][0];
#pragma unroll
        for (int nb = 0; nb < 2; ++nb)
#pragma unroll
            for (int r = 0; r < 16; ++r) pm = fmaxf(pm, sa[nb][r]);
        pm = swap_max(pm);
        if (!__all(pm <= mr + DTHR)) {
            float mn = fmaxf(mr, pm);
            float corr = EXP2(mr - mn);
            mr = mn;
            lr *= corr;
#pragma unroll
            for (int db = 0; db < 2; ++db)
#pragma unroll
                for (int r = 0; r < 16; ++r) Oacc[db][r] *= corr;
        }

        // ---- fused exp + P-frag + PV (R12-exact) ----------------------------
        float ps = 0.f;
        __builtin_amdgcn_s_setprio(1);
#pragma unroll
        for (int nb = 0; nb < 2; ++nb)
#pragma unroll
            for (int ksl = 0; ksl < 2; ++ksl) {
                float x0 = EXP2(sa[nb][8 * ksl + 0] - mr);
                float x1 = EXP2(sa[nb][8 * ksl + 1] - mr);
                float x2 = EXP2(sa[nb][8 * ksl + 2] - mr);
                float x3 = EXP2(sa[nb][8 * ksl + 3] - mr);
                float x4 = EXP2(sa[nb][8 * ksl + 4] - mr);
                float x5 = EXP2(sa[nb][8 * ksl + 5] - mr);
                float x6 = EXP2(sa[nb][8 * ksl + 6] - mr);
                float x7 = EXP2(sa[nb][8 * ksl + 7] - mr);
                ps += ((x0 + x1) + (x2 + x3)) + ((x4 + x5) + (x6 + x7));
                u32 w0 = PKRTZ(x0, x1);
                u32 w1 = PKRTZ(x2, x3);
                u32 w2 = PKRTZ(x4, x5);
                u32 w3 = PKRTZ(x6, x7);
                PLSWAP(w0, w2);
                PLSWAP(w1, w3);
                uint4 pu = {w0, w1, w2, w3};
                f16x8_t pfrag = __builtin_bit_cast(f16x8_t, pu);
                const int ks = nb * 2 + ksl;
                s16x8_t v0 = *(const s16x8_t*)(pool + bo + rowb + vcol[ks]);
                s16x8_t v1 = *(const s16x8_t*)(pool + bo + rowb + (vcol[ks] ^ 0x40u) + 32 * ROWB);
                Oacc[0] = MFMA32(__builtin_bit_cast(f16x8_t, v0), pfrag, Oacc[0], 0, 0, 0);
                Oacc[1] = MFMA32(__builtin_bit_cast(f16x8_t, v1), pfrag, Oacc[1], 0, 0, 0);
            }
        __builtin_amdgcn_s_setprio(0);
        lr += swap_add(ps);
    };

    // ---- main loop: each half runs its own 8 tiles; barriers block-wide -----
    {
        float4 a0, a1, c0, c1;
        loadtile(0, a0, a1, c0, c1);
        stage_write(hoff, a0, a1, c0, c1);
    }
    __syncthreads();
    for (int t = 0; t < HTILES; t += 2) {
        {
            compute(hoff);
            float4 a0, a1, c0, c1;
            loadtile(t + 1, a0, a1, c0, c1);
            stage_write(hoff + BUF_STRIDE, a0, a1, c0, c1);
            __syncthreads();
        }
        {
            compute(hoff + BUF_STRIDE);
            if (t + 2 < HTILES) {
                float4 a0, a1, c0, c1;
                loadtile(t + 2, a0, a1, c0, c1);
                stage_write(hoff, a0, a1, c0, c1);
            }
            __syncthreads();
        }
    }

    // ---- merge halves (element-wise per lane; same lane->(q,d) map) ---------
    // mergebuf: [group][lane][34] f32 = 34816 B at pool+0 (tile data dead now)
    float* mb = (float*)pool + ((size_t)wg * 64 + lane) * 34;
    if (wh == 1) {
#pragma unroll
        for (int db = 0; db < 2; ++db)
#pragma unroll
            for (int r = 0; r < 16; ++r) mb[db * 16 + r] = Oacc[db][r];
        mb[32] = mr;
        mb[33] = lr;
    }
    __syncthreads();
    float inv = 0.f;
    if (wh == 0) {
        float mB = mb[32], lB = mb[33];
        float m  = fmaxf(mr, mB);
        float cA = EXP2(mr - m), cB = EXP2(mB - m);
        float lfull = lr * cA + lB * cB;
        inv = 1.0f / lfull;
#pragma unroll
        for (int db = 0; db < 2; ++db)
#pragma unroll
            for (int r = 0; r < 16; ++r)
                Oacc[db][r] = Oacc[db][r] * cA + mb[db * 16 + r] * cB;
    }
    __syncthreads();   // merge reads done before fp overwrites pool

    // ---- epilogue: waves 0-3 write fp[128][68]; all 512 store coalesced -----
    float* fp = (float*)pool;
    if (wh == 0) {
#pragma unroll
        for (int db = 0; db < 2; ++db)
#pragma unroll
            for (int r = 0; r < 16; ++r) {
                int d = db * 32 + (r & 3) + 8 * (r >> 2) + 4 * hi;
                fp[(wg * 32 + l31) * 68 + d] = Oacc[db][r] * inv;
            }
    }
    __syncthreads();
    {
        const int row = tid >> 2, ch = tid & 3;    // 128 rows x 4 chunks(16 floats)
        const float* srcp = fp + row * 68 + ch * 16;
        float* dst = outp + ((size_t)b * SEQc + qt * QT + row) * HIDc + h * 64 + ch * 16;
#pragma unroll
        for (int k = 0; k < 4; ++k)
            *(float4*)(dst + k * 4) = *(const float4*)(srcp + k * 4);
    }
}

extern "C" void kernel_launch(void* const* d_in, const int* in_sizes, int n_in,
                              void* d_out, int out_size, void* d_ws, size_t ws_size,
                              hipStream_t stream) {
    const float* X    = (const float*)d_in[0];
    const float* Y    = (const float*)d_in[1];
    const float* padx = (const float*)d_in[2];
    const float* pady = (const float*)d_in[3];
    float* out = (float*)d_out;
    (void)in_sizes; (void)n_in; (void)out_size; (void)d_ws; (void)ws_size;

    dim3 grid(SEQc / QT, Bb * 8, 2);
    hipLaunchKernelGGL(xattn_kernel, grid, dim3(512), 0, stream, X, Y, padx, pady, out);
}

// Round 20
// 106.102 us; speedup vs baseline: 1.0690x; 1.0690x over previous
//
#include <hip/hip_runtime.h>
#include <hip/hip_bf16.h>
#include <stdint.h>

typedef _Float16 f16x8_t  __attribute__((ext_vector_type(8)));
typedef float    f32x16_t __attribute__((ext_vector_type(16)));
typedef short    s16x8_t  __attribute__((ext_vector_type(8)));
typedef unsigned uint2v   __attribute__((ext_vector_type(2)));
typedef unsigned int u32;

#define MFMA32 __builtin_amdgcn_mfma_f32_32x32x16_f16

#if __has_builtin(__builtin_amdgcn_exp2f)
#define EXP2(x) __builtin_amdgcn_exp2f(x)
#else
#define EXP2(x) exp2f(x)
#endif

__device__ __forceinline__ u32 PKRTZ(float a, float b) {
    return __builtin_bit_cast(u32, __builtin_amdgcn_cvt_pkrtz(a, b));
}

// permlane32_swap: exchanges hi-half of a with lo-half of b (builtin, no aliasing hazard)
__device__ __forceinline__ void PLSWAP(u32& a, u32& b) {
#if __has_builtin(__builtin_amdgcn_permlane32_swap)
    uint2v r = __builtin_amdgcn_permlane32_swap(a, b, false, false);
    a = r[0]; b = r[1];
#else
    u32 pa = (u32)__shfl_xor((int)a, 32);
    u32 pb = (u32)__shfl_xor((int)b, 32);
    const int hi_ = (int)((threadIdx.x & 63) >> 5);
    u32 na = hi_ ? pb : a;
    u32 nb = hi_ ? b  : pa;
    a = na; b = nb;
#endif
}
__device__ __forceinline__ float swap_add(float v) {   // own + partner(lane^32)
    u32 a = __builtin_bit_cast(u32, v), b = a;
    PLSWAP(a, b);
    return __builtin_bit_cast(float, a) + __builtin_bit_cast(float, b);
}
__device__ __forceinline__ float swap_max(float v) {
    u32 a = __builtin_bit_cast(u32, v), b = a;
    PLSWAP(a, b);
    return fmaxf(__builtin_bit_cast(float, a), __builtin_bit_cast(float, b));
}

constexpr int Bb   = 16;
constexpr int HIDc = 512;
constexpr int SEQc = 1024;

constexpr int QT = 128;            // q rows per block (4 waves x 32)
constexpr int KT = 64;             // kv rows per tile
constexpr int NTILES = SEQc / KT;  // 16

constexpr float LOG2E_F = 1.4426950408889634f;
constexpr float DTHR    = 11.5f;   // defer-max threshold (log2 domain)

constexpr int ROWB       = 144;            // 72 f16 per row
constexpr int VT_OFF     = 64 * ROWB;      // 9216 (within buffer)
constexpr int BUF_STRIDE = 2 * VT_OFF;     // 18432 (K + Vt)
constexpr int LDS_TOTAL  = 2 * BUF_STRIDE; // 36864; epilogue needs 34816

__global__ __launch_bounds__(256, 4)
void xattn_kernel(const float* __restrict__ X, const float* __restrict__ Y,
                  const float* __restrict__ padx, const float* __restrict__ pady,
                  float* __restrict__ out)
{
    __shared__ __align__(16) unsigned char pool[LDS_TOTAL];

    const int tid  = threadIdx.x;
    const int w    = tid >> 6;
    const int lane = tid & 63;
    const int l31  = lane & 31;
    const int hi   = lane >> 5;

    // XCD-aware swizzle (nwg=2048, bijective): 8 q-tile blocks/KV-panel -> same XCD
    const unsigned hid = blockIdx.x + gridDim.x * (blockIdx.y + gridDim.y * blockIdx.z);
    const unsigned lid = (hid & 7u) * 256u + (hid >> 3);
    const int qt   = lid & 7;
    const int bh   = (lid >> 3) & 127;
    const int pass = lid >> 10;
    const int b    = bh >> 3;
    const int h    = bh & 7;

    // pass 0: Q=X, KV=[pad_y;Y] -> Y_in_X (output 1)
    // pass 1: Q=Y, KV=[pad_x;X] -> X_in_Y (output 0)
    const float* Qp   = pass == 0 ? X : Y;
    const float* KVp  = pass == 0 ? Y : X;
    const float* padp = pass == 0 ? pady : padx;
    float* outp = out + (pass == 0 ? (size_t)Bb * SEQc * HIDc : (size_t)0);

    // ---- Q fragments (B-operand 32x32x16): col=q=l31, slot(hi,j) -> d=ds*16+hi*8+j
    const float* qrow = Qp + ((size_t)b * SEQc + qt * QT + w * 32 + l31) * HIDc + h * 64;
    f16x8_t qf[4];
#pragma unroll
    for (int ds = 0; ds < 4; ++ds) {
        const float* src = qrow + ds * 16 + hi * 8;
        float4 a = *(const float4*)src;
        float4 c = *(const float4*)(src + 4);
        uint4 uu = {PKRTZ(a.x * LOG2E_F, a.y * LOG2E_F), PKRTZ(a.z * LOG2E_F, a.w * LOG2E_F),
                    PKRTZ(c.x * LOG2E_F, c.y * LOG2E_F), PKRTZ(c.z * LOG2E_F, c.w * LOG2E_F)};
        qf[ds] = __builtin_bit_cast(f16x8_t, uu);
    }

    // ---- pad prologue (log2-domain scores via scaled Q) ----------------------
    const float* padh = padp + h * 64;
    float s0 = 0.f, s1 = 0.f;
#pragma unroll
    for (int ds = 0; ds < 4; ++ds)
#pragma unroll
        for (int j = 0; j < 8; ++j) {
            float qv = (float)qf[ds][j];
            int d = ds * 16 + hi * 8 + j;
            s0 += qv * padh[d];
            s1 += qv * padh[HIDc + d];
        }
    s0 = swap_add(s0);
    s1 = swap_add(s1);
    float mr = fmaxf(s0, s1);
    float e0 = EXP2(s0 - mr), e1 = EXP2(s1 - mr);
    float lr = e0 + e1;

    // O^T acc (32x32 D-layout): col=q=l31, row=d_local=(r&3)+8*(r>>2)+4*hi, d=db*32+d_local
    f32x16_t Oacc[2];
#pragma unroll
    for (int db = 0; db < 2; ++db)
#pragma unroll
        for (int r = 0; r < 16; ++r) {
            int d = db * 32 + (r & 3) + 8 * (r >> 2) + 4 * hi;
            Oacc[db][r] = e0 * padh[d] + e1 * padh[HIDc + d];
        }

    // ---- LDS read addresses ---------------------------------------------------
    // K: 2-bit key (matches K write); Vt: 3-bit row key ((d>>3)<<4), db=1 = ^0x40
    const unsigned kkey = (unsigned)(((l31 >> 3) & 3) << 4);
    const unsigned vkey = (unsigned)((l31 >> 3) << 4);
    const unsigned rowb = (unsigned)(l31 * ROWB);
    unsigned kcol[4], vcol[4];
#pragma unroll
    for (int s = 0; s < 4; ++s) {
        kcol[s] = (unsigned)((s * 32 + hi * 16) ^ kkey);
        vcol[s] = (unsigned)(VT_OFF + ((s * 32 + hi * 16) ^ vkey));
    }

    // staging geometry: thread -> rows (2tr, 2tr+1), col-octet tc*8
    const int tr = tid >> 3, tc = tid & 7;
    const float* ksrc = KVp + ((size_t)b * SEQc + 2 * tr) * HIDc + h * 64 + tc * 8;
    const unsigned kw  = (unsigned)((2 * tr) * ROWB + ((tc * 16) ^ ((((2 * tr) >> 3) & 3) << 4)));
    // Vt write: row d = tc*8+j, byte (4*tr) ^ (tc<<4)  [3-bit key -> all 32 banks, 2-way]
    const unsigned vtw = (unsigned)(VT_OFF + (tc * 8) * ROWB + ((4 * tr) ^ (tc << 4)));

    // ---- helpers ------------------------------------------------------------
    auto loadtile = [&](int idx, float4& a0, float4& a1, float4& c0, float4& c1) {
        const float* srow = ksrc + (size_t)idx * KT * HIDc;
        a0 = *(const float4*)srow;          a1 = *(const float4*)(srow + 4);
        c0 = *(const float4*)(srow + HIDc); c1 = *(const float4*)(srow + HIDc + 4);
    };
    auto stage_write = [&](int bo, const float4& a0, const float4& a1,
                           const float4& c0, const float4& c1) {
        uint4 k0 = {PKRTZ(a0.x, a0.y), PKRTZ(a0.z, a0.w), PKRTZ(a1.x, a1.y), PKRTZ(a1.z, a1.w)};
        uint4 k1 = {PKRTZ(c0.x, c0.y), PKRTZ(c0.z, c0.w), PKRTZ(c1.x, c1.y), PKRTZ(c1.z, c1.w)};
        *(uint4*)(pool + bo + kw) = k0;
        *(uint4*)(pool + bo + kw + ROWB) = k1;
        float fa[8] = {a0.x, a0.y, a0.z, a0.w, a1.x, a1.y, a1.z, a1.w};
        float fc[8] = {c0.x, c0.y, c0.z, c0.w, c1.x, c1.y, c1.z, c1.w};
#pragma unroll
        for (int j = 0; j < 8; ++j)
            *(u32*)(pool + bo + vtw + j * ROWB) = PKRTZ(fa[j], fc[j]);
    };

    auto compute = [&](int bo) {
        // ---- S^T = K*Q^T via 32x32x16: sa[nb], kv = nb*32 + (r&3)+8*(r>>2)+4*hi
        f32x16_t sa[2];
#pragma unroll
        for (int nb = 0; nb < 2; ++nb)
#pragma unroll
            for (int r = 0; r < 16; ++r) sa[nb][r] = 0.f;
        __builtin_amdgcn_s_setprio(1);
#pragma unroll
        for (int ds = 0; ds < 4; ++ds) {
            s16x8_t k0 = *(const s16x8_t*)(pool + bo + rowb + kcol[ds]);
            s16x8_t k1 = *(const s16x8_t*)(pool + bo + rowb + kcol[ds] + 32 * ROWB);
            sa[0] = MFMA32(__builtin_bit_cast(f16x8_t, k0), qf[ds], sa[0], 0, 0, 0);
            sa[1] = MFMA32(__builtin_bit_cast(f16x8_t, k1), qf[ds], sa[1], 0, 0, 0);
        }
        __builtin_amdgcn_s_setprio(0);

        // ---- softmax max-reduce (in-lane + one permlane swap) ---------------
        float pm = sa[0][0];
#pragma unroll
        for (int nb = 0; nb < 2; ++nb)
#pragma unroll
            for (int r = 0; r < 16; ++r) pm = fmaxf(pm, sa[nb][r]);
        pm = swap_max(pm);
        if (!__all(pm <= mr + DTHR)) {
            float mn = fmaxf(mr, pm);
            float corr = EXP2(mr - mn);
            mr = mn;
            lr *= corr;
#pragma unroll
            for (int db = 0; db < 2; ++db)
#pragma unroll
                for (int r = 0; r < 16; ++r) Oacc[db][r] *= corr;
        }

        // ---- fused exp + P-frag + PV (no pe array: sa consumed in place) ----
        float ps = 0.f;
        __builtin_amdgcn_s_setprio(1);
#pragma unroll
        for (int nb = 0; nb < 2; ++nb)
#pragma unroll
            for (int ksl = 0; ksl < 2; ++ksl) {
                float x0 = EXP2(sa[nb][8 * ksl + 0] - mr);
                float x1 = EXP2(sa[nb][8 * ksl + 1] - mr);
                float x2 = EXP2(sa[nb][8 * ksl + 2] - mr);
                float x3 = EXP2(sa[nb][8 * ksl + 3] - mr);
                float x4 = EXP2(sa[nb][8 * ksl + 4] - mr);
                float x5 = EXP2(sa[nb][8 * ksl + 5] - mr);
                float x6 = EXP2(sa[nb][8 * ksl + 6] - mr);
                float x7 = EXP2(sa[nb][8 * ksl + 7] - mr);
                ps += ((x0 + x1) + (x2 + x3)) + ((x4 + x5) + (x6 + x7));
                u32 w0 = PKRTZ(x0, x1);
                u32 w1 = PKRTZ(x2, x3);
                u32 w2 = PKRTZ(x4, x5);
                u32 w3 = PKRTZ(x6, x7);
                PLSWAP(w0, w2);
                PLSWAP(w1, w3);
                uint4 pu = {w0, w1, w2, w3};
                f16x8_t pfrag = __builtin_bit_cast(f16x8_t, pu);
                const int ks = nb * 2 + ksl;
                s16x8_t v0 = *(const s16x8_t*)(pool + bo + rowb + vcol[ks]);
                s16x8_t v1 = *(const s16x8_t*)(pool + bo + rowb + (vcol[ks] ^ 0x40u) + 32 * ROWB);
                Oacc[0] = MFMA32(__builtin_bit_cast(f16x8_t, v0), pfrag, Oacc[0], 0, 0, 0);
                Oacc[1] = MFMA32(__builtin_bit_cast(f16x8_t, v1), pfrag, Oacc[1], 0, 0, 0);
            }
        __builtin_amdgcn_s_setprio(0);
        lr += swap_add(ps);
    };

    // ---- main KV loop: double-buffered, one barrier per tile ----------------
    {
        float4 a0, a1, c0, c1;
        loadtile(0, a0, a1, c0, c1);
        stage_write(0, a0, a1, c0, c1);
    }
    __syncthreads();
    for (int kt = 0; kt < NTILES; kt += 2) {
        {
            compute(0);
            float4 a0, a1, c0, c1;
            loadtile(kt + 1, a0, a1, c0, c1);
            stage_write(BUF_STRIDE, a0, a1, c0, c1);
            __syncthreads();
        }
        {
            compute(BUF_STRIDE);
            if (kt + 2 < NTILES) {
                float4 a0, a1, c0, c1;
                loadtile(kt + 2, a0, a1, c0, c1);
                stage_write(0, a0, a1, c0, c1);
            }
            __syncthreads();
        }
    }

    // ---- epilogue: normalize, transpose via LDS, coalesced float4 stores ----
    {
        const float inv = 1.0f / lr;
        float* fp = (float*)pool;
#pragma unroll
        for (int db = 0; db < 2; ++db)
#pragma unroll
            for (int r = 0; r < 16; ++r) {
                int d = db * 32 + (r & 3) + 8 * (r >> 2) + 4 * hi;
                fp[(w * 32 + l31) * 68 + d] = Oacc[db][r] * inv;
            }
    }
    __syncthreads();
    {
        const int row = tid >> 1, ch = tid & 1;
        const float* srcp = (const float*)pool + row * 68 + ch * 32;
        float* dst = outp + ((size_t)b * SEQc + qt * QT + row) * HIDc + h * 64 + ch * 32;
#pragma unroll
        for (int k = 0; k < 8; ++k)
            *(float4*)(dst + k * 4) = *(const float4*)(srcp + k * 4);
    }
}

extern "C" void kernel_launch(void* const* d_in, const int* in_sizes, int n_in,
                              void* d_out, int out_size, void* d_ws, size_t ws_size,
                              hipStream_t stream) {
    const float* X    = (const float*)d_in[0];
    const float* Y    = (const float*)d_in[1];
    const float* padx = (const float*)d_in[2];
    const float* pady = (const float*)d_in[3];
    float* out = (float*)d_out;
    (void)in_sizes; (void)n_in; (void)out_size; (void)d_ws; (void)ws_size;

    dim3 grid(SEQc / QT, Bb * 8, 2);
    hipLaunchKernelGGL(xattn_kernel, grid, dim3(256), 0, stream, X, Y, padx, pady, out);
}